// Round 12
// baseline (133.716 us; speedup 1.0000x reference)
//
#include <hip/hip_runtime.h>
#include <hip/hip_bf16.h>

typedef __bf16 bf16;
typedef __bf16 bf16x8 __attribute__((ext_vector_type(8)));
typedef float  f32x4  __attribute__((ext_vector_type(4)));
typedef float  f32x16 __attribute__((ext_vector_type(16)));
typedef unsigned int u32;
typedef u32 u32x4 __attribute__((ext_vector_type(4)));

#define AS1 __attribute__((address_space(1)))
#define AS3 __attribute__((address_space(3)))

#define T_LEN 2048
#define EMB   1280
#define NH    20
#define HD    64

#define NCHUNK_PER_HEAD 40

// 0.125 (=1/sqrt(64)) * log2(e)
#define QSCALE 0.18033688011112042f

__device__ __forceinline__ void gl_lds16(const void* gsrc, void* ldst) {
  __builtin_amdgcn_global_load_lds((AS1 void*)const_cast<void*>(gsrc),
                                   (AS3 void*)ldst, 16, 0, 0);
}

// ---------------- cvt ----------------
__global__ __launch_bounds__(256) void cvt_all(
    const float* __restrict__ hs, const float* __restrict__ wq,
    const float* __restrict__ wk, const float* __restrict__ wv,
    const float* __restrict__ wo, bf16* __restrict__ out) {
  const int HS8 = T_LEN * EMB / 8;
  const int W8  = EMB * EMB / 8;
  int i = blockIdx.x * 256 + threadIdx.x;
  const float* src;
  bf16* dst;
  int off;
  if (i < HS8)              { src = hs; dst = out;                              off = i; }
  else if (i < HS8 + W8)    { src = wq; dst = out + (size_t)T_LEN * EMB;        off = i - HS8; }
  else if (i < HS8 + 2*W8)  { src = wk; dst = out + (size_t)T_LEN*EMB +   (size_t)EMB*EMB; off = i - HS8 - W8; }
  else if (i < HS8 + 3*W8)  { src = wv; dst = out + (size_t)T_LEN*EMB + 2*(size_t)EMB*EMB; off = i - HS8 - 2*W8; }
  else if (i < HS8 + 4*W8)  { src = wo; dst = out + (size_t)T_LEN*EMB + 3*(size_t)EMB*EMB; off = i - HS8 - 3*W8; }
  else return;
  const float4* p4 = (const float4*)src;
  float4 a = p4[2 * off], b = p4[2 * off + 1];
  bf16x8 o;
  o[0] = (bf16)a.x; o[1] = (bf16)a.y; o[2] = (bf16)a.z; o[3] = (bf16)a.w;
  o[4] = (bf16)b.x; o[5] = (bf16)b.y; o[6] = (bf16)b.z; o[7] = (bf16)b.w;
  *(bf16x8*)(dst + (size_t)off * 8) = o;
}

// ---------------- QKV GEMM: A in registers, B via LDS ----------------
// 128x128 tile, 4 waves (2x2), BK=64. A-fragments double-buffered in two NAMED
// register sets (afA/afB) prefetched 1 K-tile ahead from global (L2-resident via
// XCD-rectangle decode). Only B staged through LDS -> LDS-pipe traffic ~halved.
// vmcnt(16) = this iter's 8 B-stage + 8 A-loads in flight; older ops drained.
__global__ __launch_bounds__(256, 2) void gemm_qkv(
    const bf16* __restrict__ hsb,
    const bf16* __restrict__ wqb, const bf16* __restrict__ wkb,
    const bf16* __restrict__ wvb,
    const float* __restrict__ bq, const float* __restrict__ bv,
    bf16* __restrict__ Qb, bf16* __restrict__ Kb, bf16* __restrict__ VTb)
{
  constexpr int NK = EMB / 64;          // 20
  __shared__ alignas(16) bf16 Bs[2][128 * 64];

  const int g = blockIdx.x & 7, local = blockIdx.x >> 3;
  const int sub = local / 10;
  const int bn = local % 10;
  const int bm = g * 2 + (sub & 1);
  const int mode = sub >> 1;
  const bf16* B = (mode == 0) ? wqb : (mode == 1) ? wkb : wvb;
  const int rowbase = bm * 128;

  const int lane = threadIdx.x & 63;
  const int w = threadIdx.x >> 6;
  const int wr = w >> 1, wc = w & 1;
  const int g4 = lane >> 4, c = lane & 15;

  const f32x4 z4 = {0.f, 0.f, 0.f, 0.f};
  f32x4 acc[4][4];
  #pragma unroll
  for (int i = 0; i < 4; ++i)
    #pragma unroll
    for (int j = 0; j < 4; ++j) acc[i][j] = z4;

  // per-lane base for A-fragment loads: row = rowbase + wr*64 + mt*16 + c,
  // byte-in-row = kt*128 + kc*64 + g4*16 (identical bytes to the old LDS frag)
  const char* Abase = (const char*)hsb + (size_t)(rowbase + wr * 64 + c) * (EMB * 2) + g4 * 16;

  auto STAGE_B = [&](int b, int kt) {
    #pragma unroll
    for (int i = 0; i < 4; ++i) {
      const int call = w * 4 + i;
      const int slot = call * 1024 + lane * 16;
      const int row = slot >> 7;
      const int scb = (slot & 127) ^ ((row & 7) << 4);
      gl_lds16((const char*)B + (size_t)(bn * 128 + row) * (EMB * 2) + kt * 128 + scb,
               (char*)Bs[b] + call * 1024);
    }
  };

  bf16x8 afA[8], afB[8];

  // prologue: B(0) -> Bs[0]; A(0) -> afA   (16 vmem ops in flight)
  STAGE_B(0, 0);
  #pragma unroll
  for (int mt = 0; mt < 4; ++mt)
    #pragma unroll
    for (int kc = 0; kc < 2; ++kc)
      afA[mt * 2 + kc] = *(const bf16x8*)(Abase + mt * (16 * EMB * 2) + kc * 64);

#define QKV_STEP(CURA, NXTA, CURB, NXTB, KT)                                   \
  {                                                                            \
    const int ktn_ = ((KT) + 1 < NK) ? (KT) + 1 : (KT);                        \
    STAGE_B(NXTB, ktn_);                                                       \
    _Pragma("unroll")                                                          \
    for (int mt = 0; mt < 4; ++mt)                                             \
      _Pragma("unroll")                                                        \
      for (int kc = 0; kc < 2; ++kc)                                           \
        af##NXTA[mt * 2 + kc] = *(const bf16x8*)(Abase + mt * (16 * EMB * 2)   \
                                + (size_t)ktn_ * 128 + kc * 64);               \
    asm volatile("s_waitcnt vmcnt(16)" ::: "memory");                          \
    __builtin_amdgcn_s_barrier();                                              \
    asm volatile("" ::: "memory");                                             \
    const bf16* Bsc = Bs[CURB];                                                \
    _Pragma("unroll")                                                          \
    for (int kc = 0; kc < 2; ++kc) {                                           \
      bf16x8 bfr[4];                                                           \
      _Pragma("unroll")                                                        \
      for (int nt = 0; nt < 4; ++nt) {                                         \
        const int row = wc * 64 + nt * 16 + c;                                 \
        const int off = row * 128 + ((kc * 64 + g4 * 16) ^ ((row & 7) << 4));  \
        bfr[nt] = *(const bf16x8*)((const char*)Bsc + off);                    \
      }                                                                        \
      _Pragma("unroll")                                                        \
      for (int mt = 0; mt < 4; ++mt)                                           \
        _Pragma("unroll")                                                      \
        for (int nt = 0; nt < 4; ++nt)                                         \
          acc[mt][nt] = __builtin_amdgcn_mfma_f32_16x16x32_bf16(               \
              af##CURA[mt * 2 + kc], bfr[nt], acc[mt][nt], 0, 0, 0);           \
    }                                                                          \
    asm volatile("" ::: "memory");                                             \
    __builtin_amdgcn_s_barrier();                                              \
  }

  for (int kt = 0; kt < NK; kt += 2) {
    QKV_STEP(A, B, 0, 1, kt);
    QKV_STEP(B, A, 1, 0, kt + 1);
  }
#undef QKV_STEP

  // epilogue: C/D layout col=lane&15, row=(lane>>4)*4+reg
  #pragma unroll
  for (int mt = 0; mt < 4; ++mt) {
    const int t0 = rowbase + wr * 64 + mt * 16 + g4 * 4;
    #pragma unroll
    for (int nt = 0; nt < 4; ++nt) {
      const int n = bn * 128 + wc * 64 + nt * 16 + c;
      const int h = n >> 6, d = n & 63;
      #pragma unroll
      for (int r = 0; r < 4; ++r) {
        const int t = t0 + r;
        float v = acc[mt][nt][r];
        if (mode == 0) {
          v = (v + bq[n]) * QSCALE;
          Qb[((size_t)h * T_LEN + t) * HD + d] = (bf16)v;
        } else if (mode == 1) {
          Kb[((size_t)h * T_LEN + t) * HD + d] = (bf16)v;
        } else {
          v += bv[n];
          VTb[((size_t)h * HD + d) * T_LEN + t] = (bf16)v;
        }
      }
    }
  }
}

// ---------------- O-proj GEMM (round-9 known-good) ----------------
__global__ __launch_bounds__(128, 2) void gemm_o(
    const bf16* __restrict__ aob, const bf16* __restrict__ wob,
    const float* __restrict__ bo, float* __restrict__ Out)
{
  constexpr int NK = EMB / 64;
  __shared__ alignas(16) bf16 As[2][64 * 64];
  __shared__ alignas(16) bf16 Bs[2][64 * 64];

  const int g = blockIdx.x & 7, local = blockIdx.x >> 3;
  const int bm = g * 4 + local / 20;
  const int bn = local % 20;
  const int rowbase = bm * 64;

  const int lane = threadIdx.x & 63;
  const int w = threadIdx.x >> 6;
  const int g4 = lane >> 4, c = lane & 15;

  const f32x4 z4 = {0.f, 0.f, 0.f, 0.f};
  f32x4 acc[2][4];
  #pragma unroll
  for (int i = 0; i < 2; ++i)
    #pragma unroll
    for (int j = 0; j < 4; ++j) acc[i][j] = z4;

  auto STAGE = [&](int b, int kt) {
    #pragma unroll
    for (int i = 0; i < 4; ++i) {
      const int call = w * 4 + i;
      const int slot = call * 1024 + lane * 16;
      const int row = slot >> 7;
      const int scb = (slot & 127) ^ ((row & 7) << 4);
      gl_lds16((const char*)aob + (size_t)(rowbase + row) * (EMB * 2) + kt * 128 + scb,
               (char*)As[b] + call * 1024);
    }
    #pragma unroll
    for (int i = 0; i < 4; ++i) {
      const int call = w * 4 + i;
      const int slot = call * 1024 + lane * 16;
      const int row = slot >> 7;
      const int scb = (slot & 127) ^ ((row & 7) << 4);
      gl_lds16((const char*)wob + (size_t)(bn * 64 + row) * (EMB * 2) + kt * 128 + scb,
               (char*)Bs[b] + call * 1024);
    }
  };

  STAGE(0, 0);
  for (int kt = 0; kt < NK; ++kt) {
    const int cur = kt & 1;
    STAGE(cur ^ 1, kt + 1 < NK ? kt + 1 : kt);
    asm volatile("s_waitcnt vmcnt(8)" ::: "memory");
    __builtin_amdgcn_s_barrier();
    asm volatile("" ::: "memory");
    const bf16* Asc = As[cur];
    const bf16* Bsc = Bs[cur];
    #pragma unroll
    for (int kc = 0; kc < 2; ++kc) {
      bf16x8 af[2], bfr[4];
      #pragma unroll
      for (int mt = 0; mt < 2; ++mt) {
        const int row = w * 32 + mt * 16 + c;
        const int off = row * 128 + ((kc * 64 + g4 * 16) ^ ((row & 7) << 4));
        af[mt] = *(const bf16x8*)((const char*)Asc + off);
      }
      #pragma unroll
      for (int nt = 0; nt < 4; ++nt) {
        const int row = nt * 16 + c;
        const int off = row * 128 + ((kc * 64 + g4 * 16) ^ ((row & 7) << 4));
        bfr[nt] = *(const bf16x8*)((const char*)Bsc + off);
      }
      #pragma unroll
      for (int mt = 0; mt < 2; ++mt)
        #pragma unroll
        for (int nt = 0; nt < 4; ++nt)
          acc[mt][nt] = __builtin_amdgcn_mfma_f32_16x16x32_bf16(af[mt], bfr[nt],
                                                                acc[mt][nt], 0, 0, 0);
    }
    asm volatile("" ::: "memory");
    __builtin_amdgcn_s_barrier();
  }

  #pragma unroll
  for (int mt = 0; mt < 2; ++mt) {
    const int t0 = rowbase + w * 32 + mt * 16 + g4 * 4;
    #pragma unroll
    for (int nt = 0; nt < 4; ++nt) {
      const int n = bn * 64 + nt * 16 + c;
      #pragma unroll
      for (int r = 0; r < 4; ++r)
        Out[(size_t)(t0 + r) * EMB + n] = acc[mt][nt][r] + bo[n];
    }
  }
}

// ---------------- flash attention: split-KV, chunk=8, XCD-grouped heads ----------------
__global__ __launch_bounds__(256, 4) void attn_fwd(
    const bf16* __restrict__ Qb, const bf16* __restrict__ Kb,
    const bf16* __restrict__ VTb, bf16* __restrict__ AOb,
    bf16* __restrict__ Pob, float* __restrict__ Pml)
{
  __shared__ alignas(16) bf16 kbuf[2][64 * 64];
  __shared__ alignas(16) bf16 vbuf[2][64 * 64];

  const int g8  = blockIdx.x & 7;
  const int ord = g8 * 100 + (blockIdx.x >> 3);
  const int h   = ord / NCHUNK_PER_HEAD;
  const int idx = (NCHUNK_PER_HEAD - 1) - ord % NCHUNK_PER_HEAD;
  int qb, ch, nch;
  if (idx < 4)       { qb = idx;                ch = 0;      nch = 1; }
  else if (idx < 12) { int t = idx - 4;  qb = 4 + (t >> 1);  ch = t & 1;  nch = 2; }
  else if (idx < 24) { int t = idx - 12; qb = 8 + t / 3;     ch = t % 3;  nch = 3; }
  else               { int t = idx - 24; qb = 12 + (t >> 2); ch = t & 3;  nch = 4; }
  const int nj = 2 * qb + 2;
  const int j0 = ch * 8;
  const int j1 = (j0 + 8 < nj) ? j0 + 8 : nj;

  const int lane = threadIdx.x & 63;
  const int w  = threadIdx.x >> 6;
  const int l31 = lane & 31;
  const int hi  = lane >> 5;
  const int q0 = qb * 128;
  const int q  = q0 + w * 32 + l31;

  bf16x8 qf[4];
  {
    const char* qrow = (const char*)Qb + ((size_t)h * T_LEN + q) * (HD * 2);
    #pragma unroll
    for (int ds = 0; ds < 4; ++ds)
      qf[ds] = *(const bf16x8*)(qrow + ds * 32 + hi * 16);
  }

  f32x16 oacc[2];
  #pragma unroll
  for (int r = 0; r < 16; ++r) { oacc[0][r] = 0.f; oacc[1][r] = 0.f; }
  float m_r = -1e30f, ls = 0.f;

  auto STAGE = [&](int b, int j) {
    const int s0 = j * 64;
    #pragma unroll
    for (int i = 0; i < 2; ++i) {
      const int call = w * 2 + i;
      const int slot = call * 1024 + lane * 16;
      const int row = slot >> 7;
      const int col = (slot & 127) ^ ((row & 7) << 4);
      gl_lds16((const char*)Kb + ((size_t)h * T_LEN + s0 + row) * (HD * 2) + col,
               (char*)kbuf[b] + call * 1024);
      gl_lds16((const char*)VTb + (((size_t)h * HD + row) * T_LEN + s0) * 2 + col,
               (char*)vbuf[b] + call * 1024);
    }
  };

  auto AFRAG = [&](const bf16* buf, int rblk, int colb) -> bf16x8 {
    const int row = rblk * 32 + l31;
    const int off = row * 128 + ((colb + hi * 16) ^ ((row & 7) << 4));
    return *(const bf16x8*)((const char*)buf + off);
  };

  STAGE(0, j0);
  int cur = 0;
  for (int j = j0; j < j1; ++j) {
    STAGE(cur ^ 1, j + 1 < j1 ? j + 1 : j);
    asm volatile("s_waitcnt vmcnt(4)" ::: "memory");
    __builtin_amdgcn_s_barrier();
    asm volatile("" ::: "memory");

    f32x16 sv[2];
    #pragma unroll
    for (int r = 0; r < 16; ++r) { sv[0][r] = 0.f; sv[1][r] = 0.f; }
    #pragma unroll
    for (int ds = 0; ds < 4; ++ds) {
      #pragma unroll
      for (int sb = 0; sb < 2; ++sb) {
        bf16x8 kf = AFRAG(kbuf[cur], sb, ds * 32);
        sv[sb] = __builtin_amdgcn_mfma_f32_32x32x16_bf16(kf, qf[ds], sv[sb], 0, 0, 0);
      }
    }

    if (j >= 2 * qb) {
      const int s0 = j * 64;
      #pragma unroll
      for (int sb = 0; sb < 2; ++sb)
        #pragma unroll
        for (int r = 0; r < 16; ++r) {
          const int s = s0 + sb * 32 + (r & 3) + 8 * (r >> 2) + 4 * hi;
          if (s > q) sv[sb][r] = -1e30f;
        }
    }

    float pm = sv[0][0];
    #pragma unroll
    for (int r = 1; r < 16; ++r) pm = fmaxf(pm, sv[0][r]);
    #pragma unroll
    for (int r = 0; r < 16; ++r) pm = fmaxf(pm, sv[1][r]);
    pm = fmaxf(pm, __shfl_xor(pm, 32));
    if (!__all(pm <= m_r)) {
      const float mn = fmaxf(m_r, pm);
      const float sc = __builtin_amdgcn_exp2f(m_r - mn);
      m_r = mn;
      ls *= sc;
      oacc[0] *= sc;
      oacc[1] *= sc;
    }
    float ps = 0.f;
    #pragma unroll
    for (int sb = 0; sb < 2; ++sb)
      #pragma unroll
      for (int r = 0; r < 16; ++r) {
        const float p = __builtin_amdgcn_exp2f(sv[sb][r] - m_r);
        sv[sb][r] = p;
        ps += p;
      }
    ls += ps;

    u32 wds[16], xds[16];
    #pragma unroll
    for (int i = 0; i < 8; ++i) {
      asm("v_cvt_pk_bf16_f32 %0, %1, %2" : "=v"(wds[i])     : "v"(sv[0][2*i]), "v"(sv[0][2*i+1]));
      asm("v_cvt_pk_bf16_f32 %0, %1, %2" : "=v"(wds[8 + i]) : "v"(sv[1][2*i]), "v"(sv[1][2*i+1]));
    }
    #pragma unroll
    for (int i = 0; i < 16; ++i) xds[i] = (u32)__shfl_xor((int)wds[i], 32);

    #pragma unroll
    for (int ks = 0; ks < 4; ++ks) {
      const int o = (ks >> 1) * 8 + (ks & 1) * 4;
      u32x4 fw;
      fw.x = hi ? xds[o + 2] : wds[o];
      fw.y = hi ? xds[o + 3] : wds[o + 1];
      fw.z = hi ? wds[o + 2] : xds[o];
      fw.w = hi ? wds[o + 3] : xds[o + 1];
      bf16x8 pf = __builtin_bit_cast(bf16x8, fw);
      #pragma unroll
      for (int db = 0; db < 2; ++db) {
        bf16x8 vf = AFRAG(vbuf[cur], db, ks * 32);
        oacc[db] = __builtin_amdgcn_mfma_f32_32x32x16_bf16(vf, pf, oacc[db], 0, 0, 0);
      }
    }

    asm volatile("" ::: "memory");
    __builtin_amdgcn_s_barrier();
    cur ^= 1;
  }

  const float lt = ls + __shfl_xor(ls, 32);

  if (nch == 1) {
    const float inv = 1.f / lt;
    char* orow = (char*)AOb + ((size_t)q * EMB + h * HD) * 2;
    #pragma unroll
    for (int db = 0; db < 2; ++db)
      #pragma unroll
      for (int i = 0; i < 8; ++i) {
        const float lo = oacc[db][2 * i] * inv;
        const float hv = oacc[db][2 * i + 1] * inv;
        u32 pk;
        asm("v_cvt_pk_bf16_f32 %0, %1, %2" : "=v"(pk) : "v"(lo), "v"(hv));
        const int d = db * 32 + 8 * (i >> 1) + 2 * (i & 1) + 4 * hi;
        *(u32*)(orow + d * 2) = pk;
      }
  } else {
    const int pi = h * NCHUNK_PER_HEAD + idx;
    const int rowloc = w * 32 + l31;
    bf16* pr = Pob + ((size_t)pi * 128 + rowloc) * 64;
    #pragma unroll
    for (int db = 0; db < 2; ++db)
      #pragma unroll
      for (int i = 0; i < 8; ++i) {
        u32 pk;
        asm("v_cvt_pk_bf16_f32 %0, %1, %2" : "=v"(pk) : "v"(oacc[db][2*i]), "v"(oacc[db][2*i+1]));
        const int d = db * 32 + 8 * (i >> 1) + 2 * (i & 1) + 4 * hi;
        *(u32*)((char*)pr + d * 2) = pk;
      }
    if (hi == 0) {
      float* ml = Pml + ((size_t)pi * 128 + rowloc) * 2;
      ml[0] = m_r;
      ml[1] = lt;
    }
  }
}

// Combine partials for qb>=4 rows. One wave per q-row, lane = d.
__global__ __launch_bounds__(256) void attn_combine(
    const bf16* __restrict__ Pob, const float* __restrict__ Pml,
    bf16* __restrict__ AOb)
{
  const int gw = (blockIdx.x * 256 + threadIdx.x) >> 6;
  const int lane = threadIdx.x & 63;
  const int h  = gw / 1536;
  const int rr = gw % 1536;
  const int qb = 4 + rr / 128;
  const int rl = rr % 128;
  const int nch   = (qb < 8) ? 2 : (qb < 12) ? 3 : 4;
  const int ibase = (qb < 8) ? 4 + 2 * (qb - 4)
                   : (qb < 12) ? 12 + 3 * (qb - 8)
                   : 24 + 4 * (qb - 12);
  const int pi0 = h * NCHUNK_PER_HEAD + ibase;

  float mv[4], lv[4];
  float m = -1e30f;
  for (int c2 = 0; c2 < nch; ++c2) {
    const float* ml = Pml + ((size_t)(pi0 + c2) * 128 + rl) * 2;
    mv[c2] = ml[0];
    lv[c2] = ml[1];
    m = fmaxf(m, mv[c2]);
  }
  float acc = 0.f, l = 0.f;
  for (int c2 = 0; c2 < nch; ++c2) {
    const float sc = __builtin_amdgcn_exp2f(mv[c2] - m);
    const float ov = (float)Pob[((size_t)(pi0 + c2) * 128 + rl) * 64 + lane];
    acc += sc * ov;
    l   += sc * lv[c2];
  }
  const int qrow = qb * 128 + rl;
  AOb[(size_t)qrow * EMB + h * HD + lane] = (bf16)(acc / l);
}

extern "C" void kernel_launch(void* const* d_in, const int* in_sizes, int n_in,
                              void* d_out, int out_size, void* d_ws, size_t ws_size,
                              hipStream_t stream) {
  const float* hs = (const float*)d_in[0];
  const float* wq = (const float*)d_in[1];
  const float* bq = (const float*)d_in[2];
  const float* wk = (const float*)d_in[3];
  const float* wv = (const float*)d_in[4];
  const float* bv = (const float*)d_in[5];
  const float* wo = (const float*)d_in[6];
  const float* bo = (const float*)d_in[7];

  bf16* p = (bf16*)d_ws;
  bf16* hsb = p;  p += (size_t)T_LEN * EMB;
  bf16* wqb = p;  p += (size_t)EMB * EMB;
  bf16* wkb = p;  p += (size_t)EMB * EMB;
  bf16* wvb = p;  p += (size_t)EMB * EMB;
  bf16* wob = p;  p += (size_t)EMB * EMB;
  bf16* Qb  = p;  p += (size_t)NH * T_LEN * HD;
  bf16* Kb  = p;  p += (size_t)NH * T_LEN * HD;
  bf16* VTb = p;  p += (size_t)NH * HD * T_LEN;
  bf16* AOb = p;  p += (size_t)T_LEN * EMB;

  // Partials alias hsb/wqb/wkb/wvb (dead after gemm_qkv); 13.9 MB < 15.1 MB region.
  bf16*  Pob = (bf16*)d_ws;
  float* Pml = (float*)((char*)d_ws + (size_t)NH * NCHUNK_PER_HEAD * 128 * 64 * 2);

  const int TOT8 = T_LEN * EMB / 8 + 4 * (EMB * EMB / 8);
  cvt_all<<<(TOT8 + 255) / 256, 256, 0, stream>>>(hs, wq, wk, wv, wo, (bf16*)d_ws);

  gemm_qkv<<<dim3(480), 256, 0, stream>>>(hsb, wqb, wkb, wvb, bq, bv, Qb, Kb, VTb);
  attn_fwd<<<dim3(NH * NCHUNK_PER_HEAD), 256, 0, stream>>>(Qb, Kb, VTb, AOb, Pob, Pml);
  attn_combine<<<dim3(NH * 1536 / 4), 256, 0, stream>>>(Pob, Pml, AOb);
  gemm_o<<<dim3(640), 128, 0, stream>>>(AOb, wob, bo, (float*)d_out);
}

// Round 14
// 109.193 us; speedup vs baseline: 1.2246x; 1.2246x over previous
//
#include <hip/hip_runtime.h>
#include <hip/hip_bf16.h>

typedef __bf16 bf16;
typedef __bf16 bf16x8 __attribute__((ext_vector_type(8)));
typedef float  f32x4  __attribute__((ext_vector_type(4)));
typedef float  f32x16 __attribute__((ext_vector_type(16)));
typedef unsigned int u32;
typedef u32 u32x4 __attribute__((ext_vector_type(4)));

#define AS1 __attribute__((address_space(1)))
#define AS3 __attribute__((address_space(3)))

#define T_LEN 2048
#define EMB   1280
#define NH    20
#define HD    64

#define NCHUNK_PER_HEAD 40

// 0.125 (=1/sqrt(64)) * log2(e)
#define QSCALE 0.18033688011112042f

__device__ __forceinline__ void gl_lds16(const void* gsrc, void* ldst) {
  __builtin_amdgcn_global_load_lds((AS1 void*)const_cast<void*>(gsrc),
                                   (AS3 void*)ldst, 16, 0, 0);
}

// ---------------- cvt ----------------
__global__ __launch_bounds__(256) void cvt_all(
    const float* __restrict__ hs, const float* __restrict__ wq,
    const float* __restrict__ wk, const float* __restrict__ wv,
    const float* __restrict__ wo, bf16* __restrict__ out) {
  const int HS8 = T_LEN * EMB / 8;
  const int W8  = EMB * EMB / 8;
  int i = blockIdx.x * 256 + threadIdx.x;
  const float* src;
  bf16* dst;
  int off;
  if (i < HS8)              { src = hs; dst = out;                              off = i; }
  else if (i < HS8 + W8)    { src = wq; dst = out + (size_t)T_LEN * EMB;        off = i - HS8; }
  else if (i < HS8 + 2*W8)  { src = wk; dst = out + (size_t)T_LEN*EMB +   (size_t)EMB*EMB; off = i - HS8 - W8; }
  else if (i < HS8 + 3*W8)  { src = wv; dst = out + (size_t)T_LEN*EMB + 2*(size_t)EMB*EMB; off = i - HS8 - 2*W8; }
  else if (i < HS8 + 4*W8)  { src = wo; dst = out + (size_t)T_LEN*EMB + 3*(size_t)EMB*EMB; off = i - HS8 - 3*W8; }
  else return;
  const float4* p4 = (const float4*)src;
  float4 a = p4[2 * off], b = p4[2 * off + 1];
  bf16x8 o;
  o[0] = (bf16)a.x; o[1] = (bf16)a.y; o[2] = (bf16)a.z; o[3] = (bf16)a.w;
  o[4] = (bf16)b.x; o[5] = (bf16)b.y; o[6] = (bf16)b.z; o[7] = (bf16)b.w;
  *(bf16x8*)(dst + (size_t)off * 8) = o;
}

// ---------------- QKV GEMM (round-6/11 known-good, ~42.8 us) ----------------
__global__ __launch_bounds__(256, 2) void gemm_qkv(
    const bf16* __restrict__ hsb,
    const bf16* __restrict__ wqb, const bf16* __restrict__ wkb,
    const bf16* __restrict__ wvb,
    const float* __restrict__ bq, const float* __restrict__ bv,
    bf16* __restrict__ Qb, bf16* __restrict__ Kb, bf16* __restrict__ VTb)
{
  constexpr int NK = EMB / 64;
  __shared__ alignas(16) bf16 As[2][128 * 64];
  __shared__ alignas(16) bf16 Bs[2][128 * 64];

  const int g = blockIdx.x & 7, local = blockIdx.x >> 3;
  const int sub = local / 10;
  const int bn = local % 10;
  const int bm = g * 2 + (sub & 1);
  const int mode = sub >> 1;
  const bf16* B = (mode == 0) ? wqb : (mode == 1) ? wkb : wvb;
  const int rowbase = bm * 128;

  const int lane = threadIdx.x & 63;
  const int w = threadIdx.x >> 6;
  const int wr = w >> 1, wc = w & 1;
  const int g4 = lane >> 4, c = lane & 15;

  const f32x4 z4 = {0.f, 0.f, 0.f, 0.f};
  f32x4 acc[4][4];
  #pragma unroll
  for (int i = 0; i < 4; ++i)
    #pragma unroll
    for (int j = 0; j < 4; ++j) acc[i][j] = z4;

  auto STAGE = [&](int b, int kt) {
    #pragma unroll
    for (int i = 0; i < 4; ++i) {
      const int call = w * 4 + i;
      const int slot = call * 1024 + lane * 16;
      const int row = slot >> 7;
      const int scb = (slot & 127) ^ ((row & 7) << 4);
      gl_lds16((const char*)hsb + (size_t)(rowbase + row) * (EMB * 2) + kt * 128 + scb,
               (char*)As[b] + call * 1024);
    }
    #pragma unroll
    for (int i = 0; i < 4; ++i) {
      const int call = w * 4 + i;
      const int slot = call * 1024 + lane * 16;
      const int row = slot >> 7;
      const int scb = (slot & 127) ^ ((row & 7) << 4);
      gl_lds16((const char*)B + (size_t)(bn * 128 + row) * (EMB * 2) + kt * 128 + scb,
               (char*)Bs[b] + call * 1024);
    }
  };

  STAGE(0, 0);
  for (int kt = 0; kt < NK; ++kt) {
    const int cur = kt & 1;
    STAGE(cur ^ 1, kt + 1 < NK ? kt + 1 : kt);
    asm volatile("s_waitcnt vmcnt(8)" ::: "memory");
    __builtin_amdgcn_s_barrier();
    asm volatile("" ::: "memory");
    const bf16* Asc = As[cur];
    const bf16* Bsc = Bs[cur];
    #pragma unroll
    for (int kc = 0; kc < 2; ++kc) {
      bf16x8 af[4], bfr[4];
      #pragma unroll
      for (int mt = 0; mt < 4; ++mt) {
        const int row = wr * 64 + mt * 16 + c;
        const int off = row * 128 + ((kc * 64 + g4 * 16) ^ ((row & 7) << 4));
        af[mt] = *(const bf16x8*)((const char*)Asc + off);
      }
      #pragma unroll
      for (int nt = 0; nt < 4; ++nt) {
        const int row = wc * 64 + nt * 16 + c;
        const int off = row * 128 + ((kc * 64 + g4 * 16) ^ ((row & 7) << 4));
        bfr[nt] = *(const bf16x8*)((const char*)Bsc + off);
      }
      #pragma unroll
      for (int mt = 0; mt < 4; ++mt)
        #pragma unroll
        for (int nt = 0; nt < 4; ++nt)
          acc[mt][nt] = __builtin_amdgcn_mfma_f32_16x16x32_bf16(af[mt], bfr[nt],
                                                                acc[mt][nt], 0, 0, 0);
    }
    asm volatile("" ::: "memory");
    __builtin_amdgcn_s_barrier();
  }

  #pragma unroll
  for (int mt = 0; mt < 4; ++mt) {
    const int t0 = rowbase + wr * 64 + mt * 16 + g4 * 4;
    #pragma unroll
    for (int nt = 0; nt < 4; ++nt) {
      const int n = bn * 128 + wc * 64 + nt * 16 + c;
      const int h = n >> 6, d = n & 63;
      #pragma unroll
      for (int r = 0; r < 4; ++r) {
        const int t = t0 + r;
        float v = acc[mt][nt][r];
        if (mode == 0) {
          v = (v + bq[n]) * QSCALE;
          Qb[((size_t)h * T_LEN + t) * HD + d] = (bf16)v;
        } else if (mode == 1) {
          Kb[((size_t)h * T_LEN + t) * HD + d] = (bf16)v;
        } else {
          v += bv[n];
          VTb[((size_t)h * HD + d) * T_LEN + t] = (bf16)v;
        }
      }
    }
  }
}

// ---------------- O-proj GEMM (round-9 known-good) ----------------
__global__ __launch_bounds__(128, 2) void gemm_o(
    const bf16* __restrict__ aob, const bf16* __restrict__ wob,
    const float* __restrict__ bo, float* __restrict__ Out)
{
  constexpr int NK = EMB / 64;
  __shared__ alignas(16) bf16 As[2][64 * 64];
  __shared__ alignas(16) bf16 Bs[2][64 * 64];

  const int g = blockIdx.x & 7, local = blockIdx.x >> 3;
  const int bm = g * 4 + local / 20;
  const int bn = local % 20;
  const int rowbase = bm * 64;

  const int lane = threadIdx.x & 63;
  const int w = threadIdx.x >> 6;
  const int g4 = lane >> 4, c = lane & 15;

  const f32x4 z4 = {0.f, 0.f, 0.f, 0.f};
  f32x4 acc[2][4];
  #pragma unroll
  for (int i = 0; i < 2; ++i)
    #pragma unroll
    for (int j = 0; j < 4; ++j) acc[i][j] = z4;

  auto STAGE = [&](int b, int kt) {
    #pragma unroll
    for (int i = 0; i < 4; ++i) {
      const int call = w * 4 + i;
      const int slot = call * 1024 + lane * 16;
      const int row = slot >> 7;
      const int scb = (slot & 127) ^ ((row & 7) << 4);
      gl_lds16((const char*)aob + (size_t)(rowbase + row) * (EMB * 2) + kt * 128 + scb,
               (char*)As[b] + call * 1024);
    }
    #pragma unroll
    for (int i = 0; i < 4; ++i) {
      const int call = w * 4 + i;
      const int slot = call * 1024 + lane * 16;
      const int row = slot >> 7;
      const int scb = (slot & 127) ^ ((row & 7) << 4);
      gl_lds16((const char*)wob + (size_t)(bn * 64 + row) * (EMB * 2) + kt * 128 + scb,
               (char*)Bs[b] + call * 1024);
    }
  };

  STAGE(0, 0);
  for (int kt = 0; kt < NK; ++kt) {
    const int cur = kt & 1;
    STAGE(cur ^ 1, kt + 1 < NK ? kt + 1 : kt);
    asm volatile("s_waitcnt vmcnt(8)" ::: "memory");
    __builtin_amdgcn_s_barrier();
    asm volatile("" ::: "memory");
    const bf16* Asc = As[cur];
    const bf16* Bsc = Bs[cur];
    #pragma unroll
    for (int kc = 0; kc < 2; ++kc) {
      bf16x8 af[2], bfr[4];
      #pragma unroll
      for (int mt = 0; mt < 2; ++mt) {
        const int row = w * 32 + mt * 16 + c;
        const int off = row * 128 + ((kc * 64 + g4 * 16) ^ ((row & 7) << 4));
        af[mt] = *(const bf16x8*)((const char*)Asc + off);
      }
      #pragma unroll
      for (int nt = 0; nt < 4; ++nt) {
        const int row = nt * 16 + c;
        const int off = row * 128 + ((kc * 64 + g4 * 16) ^ ((row & 7) << 4));
        bfr[nt] = *(const bf16x8*)((const char*)Bsc + off);
      }
      #pragma unroll
      for (int mt = 0; mt < 2; ++mt)
        #pragma unroll
        for (int nt = 0; nt < 4; ++nt)
          acc[mt][nt] = __builtin_amdgcn_mfma_f32_16x16x32_bf16(af[mt], bfr[nt],
                                                                acc[mt][nt], 0, 0, 0);
    }
    asm volatile("" ::: "memory");
    __builtin_amdgcn_s_barrier();
  }

  #pragma unroll
  for (int mt = 0; mt < 2; ++mt) {
    const int t0 = rowbase + w * 32 + mt * 16 + g4 * 4;
    #pragma unroll
    for (int nt = 0; nt < 4; ++nt) {
      const int n = bn * 64 + nt * 16 + c;
      #pragma unroll
      for (int r = 0; r < 4; ++r)
        Out[(size_t)(t0 + r) * EMB + n] = acc[mt][nt][r] + bo[n];
    }
  }
}

// ---------------- flash attention: split-KV, chunk=8, XCD-grouped heads ----------------
// permlane32_swap half-exchange, CORRECTED operand order:
// v_permlane32_swap_b32 X, Y exchanges X[32:63] <-> Y[0:31]:
//   X' = {X.lower own, Y from lane-32}   -> fw.x when X=wds[o],  Y=wds[o+2]
//   Y' = {X from lane+32, Y.upper own}   -> fw.z
__global__ __launch_bounds__(256, 4) void attn_fwd(
    const bf16* __restrict__ Qb, const bf16* __restrict__ Kb,
    const bf16* __restrict__ VTb, bf16* __restrict__ AOb,
    bf16* __restrict__ Pob, float* __restrict__ Pml)
{
  __shared__ alignas(16) bf16 kbuf[2][64 * 64];
  __shared__ alignas(16) bf16 vbuf[2][64 * 64];

  const int g8  = blockIdx.x & 7;
  const int ord = g8 * 100 + (blockIdx.x >> 3);
  const int h   = ord / NCHUNK_PER_HEAD;
  const int idx = (NCHUNK_PER_HEAD - 1) - ord % NCHUNK_PER_HEAD;
  int qb, ch, nch;
  if (idx < 4)       { qb = idx;                ch = 0;      nch = 1; }
  else if (idx < 12) { int t = idx - 4;  qb = 4 + (t >> 1);  ch = t & 1;  nch = 2; }
  else if (idx < 24) { int t = idx - 12; qb = 8 + t / 3;     ch = t % 3;  nch = 3; }
  else               { int t = idx - 24; qb = 12 + (t >> 2); ch = t & 3;  nch = 4; }
  const int nj = 2 * qb + 2;
  const int j0 = ch * 8;
  const int j1 = (j0 + 8 < nj) ? j0 + 8 : nj;

  const int lane = threadIdx.x & 63;
  const int w  = threadIdx.x >> 6;
  const int l31 = lane & 31;
  const int hi  = lane >> 5;
  const int q0 = qb * 128;
  const int q  = q0 + w * 32 + l31;

  bf16x8 qf[4];
  {
    const char* qrow = (const char*)Qb + ((size_t)h * T_LEN + q) * (HD * 2);
    #pragma unroll
    for (int ds = 0; ds < 4; ++ds)
      qf[ds] = *(const bf16x8*)(qrow + ds * 32 + hi * 16);
  }

  f32x16 oacc[2];
  #pragma unroll
  for (int r = 0; r < 16; ++r) { oacc[0][r] = 0.f; oacc[1][r] = 0.f; }
  float m_r = -1e30f, ls = 0.f;

  auto STAGE = [&](int b, int j) {
    const int s0 = j * 64;
    #pragma unroll
    for (int i = 0; i < 2; ++i) {
      const int call = w * 2 + i;
      const int slot = call * 1024 + lane * 16;
      const int row = slot >> 7;
      const int col = (slot & 127) ^ ((row & 7) << 4);
      gl_lds16((const char*)Kb + ((size_t)h * T_LEN + s0 + row) * (HD * 2) + col,
               (char*)kbuf[b] + call * 1024);
      gl_lds16((const char*)VTb + (((size_t)h * HD + row) * T_LEN + s0) * 2 + col,
               (char*)vbuf[b] + call * 1024);
    }
  };

  auto AFRAG = [&](const bf16* buf, int rblk, int colb) -> bf16x8 {
    const int row = rblk * 32 + l31;
    const int off = row * 128 + ((colb + hi * 16) ^ ((row & 7) << 4));
    return *(const bf16x8*)((const char*)buf + off);
  };

  STAGE(0, j0);
  int cur = 0;
  for (int j = j0; j < j1; ++j) {
    STAGE(cur ^ 1, j + 1 < j1 ? j + 1 : j);
    asm volatile("s_waitcnt vmcnt(4)" ::: "memory");
    __builtin_amdgcn_s_barrier();
    asm volatile("" ::: "memory");

    f32x16 sv[2];
    #pragma unroll
    for (int r = 0; r < 16; ++r) { sv[0][r] = 0.f; sv[1][r] = 0.f; }
    __builtin_amdgcn_s_setprio(1);
    #pragma unroll
    for (int ds = 0; ds < 4; ++ds) {
      #pragma unroll
      for (int sb = 0; sb < 2; ++sb) {
        bf16x8 kf = AFRAG(kbuf[cur], sb, ds * 32);
        sv[sb] = __builtin_amdgcn_mfma_f32_32x32x16_bf16(kf, qf[ds], sv[sb], 0, 0, 0);
      }
    }
    __builtin_amdgcn_s_setprio(0);

    if (j >= 2 * qb) {
      const int s0 = j * 64;
      #pragma unroll
      for (int sb = 0; sb < 2; ++sb)
        #pragma unroll
        for (int r = 0; r < 16; ++r) {
          const int s = s0 + sb * 32 + (r & 3) + 8 * (r >> 2) + 4 * hi;
          if (s > q) sv[sb][r] = -1e30f;
        }
    }

    // online softmax, lane-local; exact defer-rescale (sc==1 when no new max)
    float pm = sv[0][0];
    #pragma unroll
    for (int r = 1; r < 16; ++r) pm = fmaxf(pm, sv[0][r]);
    #pragma unroll
    for (int r = 0; r < 16; ++r) pm = fmaxf(pm, sv[1][r]);
    pm = fmaxf(pm, __shfl_xor(pm, 32));
    if (!__all(pm <= m_r)) {
      const float mn = fmaxf(m_r, pm);
      const float sc = __builtin_amdgcn_exp2f(m_r - mn);
      m_r = mn;
      ls *= sc;
      oacc[0] *= sc;
      oacc[1] *= sc;
    }
    float ps = 0.f;
    #pragma unroll
    for (int sb = 0; sb < 2; ++sb)
      #pragma unroll
      for (int r = 0; r < 16; ++r) {
        const float p = __builtin_amdgcn_exp2f(sv[sb][r] - m_r);
        sv[sb][r] = p;
        ps += p;
      }
    ls += ps;

    // pack P to bf16 pairs
    u32 wds[16];
    #pragma unroll
    for (int i = 0; i < 8; ++i) {
      asm("v_cvt_pk_bf16_f32 %0, %1, %2" : "=v"(wds[i])     : "v"(sv[0][2*i]), "v"(sv[0][2*i+1]));
      asm("v_cvt_pk_bf16_f32 %0, %1, %2" : "=v"(wds[8 + i]) : "v"(sv[1][2*i]), "v"(sv[1][2*i+1]));
    }

    // PV: half-exchange via permlane32_swap (corrected operand order)
    #pragma unroll
    for (int ks = 0; ks < 4; ++ks) {
      const int o = (ks >> 1) * 8 + (ks & 1) * 4;
      u32 x0 = wds[o],     y0 = wds[o + 2];
      u32 x1 = wds[o + 1], y1 = wds[o + 3];
      asm("v_permlane32_swap_b32 %0, %1" : "+v"(x0), "+v"(y0));
      asm("v_permlane32_swap_b32 %0, %1" : "+v"(x1), "+v"(y1));
      u32x4 fw;
      fw.x = x0; fw.y = x1; fw.z = y0; fw.w = y1;
      bf16x8 pf = __builtin_bit_cast(bf16x8, fw);
      __builtin_amdgcn_s_setprio(1);
      #pragma unroll
      for (int db = 0; db < 2; ++db) {
        bf16x8 vf = AFRAG(vbuf[cur], db, ks * 32);
        oacc[db] = __builtin_amdgcn_mfma_f32_32x32x16_bf16(vf, pf, oacc[db], 0, 0, 0);
      }
      __builtin_amdgcn_s_setprio(0);
    }

    asm volatile("" ::: "memory");
    __builtin_amdgcn_s_barrier();
    cur ^= 1;
  }

  const float lt = ls + __shfl_xor(ls, 32);

  if (nch == 1) {
    const float inv = 1.f / lt;
    char* orow = (char*)AOb + ((size_t)q * EMB + h * HD) * 2;
    #pragma unroll
    for (int db = 0; db < 2; ++db)
      #pragma unroll
      for (int i = 0; i < 8; ++i) {
        const float lo = oacc[db][2 * i] * inv;
        const float hv = oacc[db][2 * i + 1] * inv;
        u32 pk;
        asm("v_cvt_pk_bf16_f32 %0, %1, %2" : "=v"(pk) : "v"(lo), "v"(hv));
        const int d = db * 32 + 8 * (i >> 1) + 2 * (i & 1) + 4 * hi;
        *(u32*)(orow + d * 2) = pk;
      }
  } else {
    const int pi = h * NCHUNK_PER_HEAD + idx;
    const int rowloc = w * 32 + l31;
    bf16* pr = Pob + ((size_t)pi * 128 + rowloc) * 64;
    #pragma unroll
    for (int db = 0; db < 2; ++db)
      #pragma unroll
      for (int i = 0; i < 8; ++i) {
        u32 pk;
        asm("v_cvt_pk_bf16_f32 %0, %1, %2" : "=v"(pk) : "v"(oacc[db][2*i]), "v"(oacc[db][2*i+1]));
        const int d = db * 32 + 8 * (i >> 1) + 2 * (i & 1) + 4 * hi;
        *(u32*)((char*)pr + d * 2) = pk;
      }
    if (hi == 0) {
      float* ml = Pml + ((size_t)pi * 128 + rowloc) * 2;
      ml[0] = m_r;
      ml[1] = lt;
    }
  }
}

// Combine partials for qb>=4 rows. One wave per q-row, lane = d.
__global__ __launch_bounds__(256) void attn_combine(
    const bf16* __restrict__ Pob, const float* __restrict__ Pml,
    bf16* __restrict__ AOb)
{
  const int gw = (blockIdx.x * 256 + threadIdx.x) >> 6;
  const int lane = threadIdx.x & 63;
  const int h  = gw / 1536;
  const int rr = gw % 1536;
  const int qb = 4 + rr / 128;
  const int rl = rr % 128;
  const int nch   = (qb < 8) ? 2 : (qb < 12) ? 3 : 4;
  const int ibase = (qb < 8) ? 4 + 2 * (qb - 4)
                   : (qb < 12) ? 12 + 3 * (qb - 8)
                   : 24 + 4 * (qb - 12);
  const int pi0 = h * NCHUNK_PER_HEAD + ibase;

  float mv[4], lv[4];
  float m = -1e30f;
  for (int c2 = 0; c2 < nch; ++c2) {
    const float* ml = Pml + ((size_t)(pi0 + c2) * 128 + rl) * 2;
    mv[c2] = ml[0];
    lv[c2] = ml[1];
    m = fmaxf(m, mv[c2]);
  }
  float acc = 0.f, l = 0.f;
  for (int c2 = 0; c2 < nch; ++c2) {
    const float sc = __builtin_amdgcn_exp2f(mv[c2] - m);
    const float ov = (float)Pob[((size_t)(pi0 + c2) * 128 + rl) * 64 + lane];
    acc += sc * ov;
    l   += sc * lv[c2];
  }
  const int qrow = qb * 128 + rl;
  AOb[(size_t)qrow * EMB + h * HD + lane] = (bf16)(acc / l);
}

extern "C" void kernel_launch(void* const* d_in, const int* in_sizes, int n_in,
                              void* d_out, int out_size, void* d_ws, size_t ws_size,
                              hipStream_t stream) {
  const float* hs = (const float*)d_in[0];
  const float* wq = (const float*)d_in[1];
  const float* bq = (const float*)d_in[2];
  const float* wk = (const float*)d_in[3];
  const float* wv = (const float*)d_in[4];
  const float* bv = (const float*)d_in[5];
  const float* wo = (const float*)d_in[6];
  const float* bo = (const float*)d_in[7];

  bf16* p = (bf16*)d_ws;
  bf16* hsb = p;  p += (size_t)T_LEN * EMB;
  bf16* wqb = p;  p += (size_t)EMB * EMB;
  bf16* wkb = p;  p += (size_t)EMB * EMB;
  bf16* wvb = p;  p += (size_t)EMB * EMB;
  bf16* wob = p;  p += (size_t)EMB * EMB;
  bf16* Qb  = p;  p += (size_t)NH * T_LEN * HD;
  bf16* Kb  = p;  p += (size_t)NH * T_LEN * HD;
  bf16* VTb = p;  p += (size_t)NH * HD * T_LEN;
  bf16* AOb = p;  p += (size_t)T_LEN * EMB;

  // Partials alias hsb/wqb/wkb/wvb (dead after gemm_qkv); 13.9 MB < 15.1 MB region.
  bf16*  Pob = (bf16*)d_ws;
  float* Pml = (float*)((char*)d_ws + (size_t)NH * NCHUNK_PER_HEAD * 128 * 64 * 2);

  const int TOT8 = T_LEN * EMB / 8 + 4 * (EMB * EMB / 8);
  cvt_all<<<(TOT8 + 255) / 256, 256, 0, stream>>>(hs, wq, wk, wv, wo, (bf16*)d_ws);

  gemm_qkv<<<dim3(480), 256, 0, stream>>>(hsb, wqb, wkb, wvb, bq, bv, Qb, Kb, VTb);
  attn_fwd<<<dim3(NH * NCHUNK_PER_HEAD), 256, 0, stream>>>(Qb, Kb, VTb, AOb, Pob, Pml);
  attn_combine<<<dim3(NH * 1536 / 4), 256, 0, stream>>>(Pob, Pml, AOb);
  gemm_o<<<dim3(640), 128, 0, stream>>>(AOb, wob, bo, (float*)d_out);
}